// Round 5
// baseline (182.958 us; speedup 1.0000x reference)
//
#include <hip/hip_runtime.h>

#define ROWS 1048576
#define BINS 17
#define RPB 128                 // rows per block = threads per block (2 waves)
#define NBLK (ROWS / RPB)       // 8192 blocks
#define NPART (2 * NBLK)        // 16384 partials per quantity (one per wave)
#define GPB (RPB / 4)           // 32 conv groups per block
#define CONV_N 33               // 2*BINS - 1
#define L2E 1.442695040888963f
#define LN2 0.6931471805599453f

// Round-5: kill the TA-transaction wall. r2-r4's scattered per-lane row
// loads cost ~64 L1 transactions per load instruction (64 lanes x stride-68B
// = 64 distinct lines): 34 instr x 64 = ~2176 txns/wave, ~139K cyc/CU ~ 58us
// -> the measured 67us wall that neither occupancy (37->62%) nor barrier
// removal moved. Fix: coalesced float4->LDS staging (16 lines/instr, ~144
// txns/block total) + per-lane ds_read rows (stride-17 odd = 2 lanes/bank,
// free) + keep r4's lean exp2 math and barrier-free in-quad DPP conv.
// Ratio repack overlays sA AFTER a barrier (all row ds_reads long done).

__device__ __forceinline__ float qx1(float v) {   // quad_perm lane^1
    return __int_as_float(__builtin_amdgcn_update_dpp(
        0, __float_as_int(v), 0xB1, 0xF, 0xF, true));
}
__device__ __forceinline__ float qx2(float v) {   // quad_perm lane^2
    return __int_as_float(__builtin_amdgcn_update_dpp(
        0, __float_as_int(v), 0x4E, 0xF, 0xF, true));
}

template <bool PART>
__global__ __launch_bounds__(128, 4) void kd_main(
    const float* __restrict__ pred,
    const float* __restrict__ soft,
    const float* __restrict__ weight,
    float* __restrict__ out,
    float* __restrict__ ws)
{
    __shared__ float sA[RPB * BINS];  // pred tile; later ratio repack overlay
    __shared__ float sB[RPB * BINS];  // soft tile
    const int tid = threadIdx.x;
    const long long base = (long long)blockIdx.x * (RPB * BINS);

    // ---- coalesced staging: 544 float4 per tile, 16 lines/instr ----
    const float4* p4 = reinterpret_cast<const float4*>(pred + base);
    const float4* q4 = reinterpret_cast<const float4*>(soft + base);
    float4* a4 = reinterpret_cast<float4*>(sA);
    float4* b4 = reinterpret_cast<float4*>(sB);
#pragma unroll
    for (int k = 0; k < 4; ++k) {
        a4[k * RPB + tid] = p4[k * RPB + tid];
        b4[k * RPB + tid] = q4[k * RPB + tid];
    }
    if (tid < 32) {
        a4[512 + tid] = p4[512 + tid];
        b4[512 + tid] = q4[512 + tid];
    }
    const float w = weight[blockIdx.x * RPB + tid];
    __syncthreads();

    // ---- per-row register loads from LDS (stride 17: 2-way alias, free) ----
    float x[BINS], y[BINS];
#pragma unroll
    for (int j = 0; j < BINS; ++j) x[j] = sA[tid * BINS + j];
#pragma unroll
    for (int j = 0; j < BINS; ++j) y[j] = sB[tid * BINS + j];

    // ---- one-pass stats ----
    float sx = 0.f, sy = 0.f, sxx = 0.f, syy = 0.f;
    float xmx = -1e30f, ymx = -1e30f;
#pragma unroll
    for (int j = 0; j < BINS; ++j) {
        sx += x[j]; sxx = fmaf(x[j], x[j], sxx); xmx = fmaxf(xmx, x[j]);
        sy += y[j]; syy = fmaf(y[j], y[j], syy); ymx = fmaxf(ymx, y[j]);
    }
    const float mx = sx * (1.0f / BINS);
    const float my = sy * (1.0f / BINS);
    const float vx = fmaxf(fmaf(-sx, mx, sxx), 0.f) * (1.0f / (BINS - 1));
    const float vy = fmaxf(fmaf(-sy, my, syy), 0.f) * (1.0f / (BINS - 1));
    // scale = (1/T) * log2(e) / (eps + std); exp2 arg = (v - vmax) * scale
    const float sxl = (0.1f * L2E) *
        __builtin_amdgcn_rcpf(1e-7f + __builtin_amdgcn_sqrtf(vx));
    const float syl = (0.1f * L2E) *
        __builtin_amdgcn_rcpf(1e-7f + __builtin_amdgcn_sqrtf(vy));
    const float cA = -xmx * sxl;
    const float cB = -ymx * syl;
    const float cT = -ymx * L2E;      // raw-y softmax, exp2 units

    // ---- fused exp pass; target exps stay in registers ----
    float et[BINS];
    float sea = 0.f, seb = 0.f, ts = 0.f, sdb = 0.f;
#pragma unroll
    for (int j = 0; j < BINS; ++j) {
        const float aj = fmaf(x[j], sxl, cA);          // log2 student logits
        const float bj = fmaf(y[j], syl, cB);          // log2 teacher logits
        const float ea = exp2f(aj);
        const float eb = exp2f(bj);
        const float tv = exp2f(fmaf(y[j], L2E, cT));
        sea += ea; seb += eb; ts += tv;
        sdb = fmaf(eb, bj - aj, sdb);                  // sum eb*(bj-aj), log2
        et[j] = tv;
    }
    // KL = ln2 * ( sum(eb*(bj-aj))/seb + log2(sea) - log2(seb) )
    const float kl = LN2 * (sdb * __builtin_amdgcn_rcpf(seb)
                            + (__log2f(sea) - __log2f(seb)));
    const float invts = __builtin_amdgcn_rcpf(ts);
#pragma unroll
    for (int j = 0; j < BINS; ++j) et[j] *= invts;     // normalized softmax

    // ---- per-wave reduce kl & weight; one partial pair per wave ----
    float k2 = kl, w2 = w;
#pragma unroll
    for (int off = 32; off >= 1; off >>= 1) {
        k2 += __shfl_down(k2, off, 64);
        w2 += __shfl_down(w2, off, 64);
    }
    if ((tid & 63) == 0) {
        const int wv = tid >> 6;
        if (PART) {
            ws[2 * blockIdx.x + wv]         = k2;
            ws[NPART + 2 * blockIdx.x + wv] = w2;
        } else {
            atomicAdd(&ws[0], k2);
            atomicAdd(&ws[1], w2);
        }
    }

    // ---- in-quad conv, no LDS, no barrier: partner row via quad_perm ----
    float f2[BINS];
#pragma unroll
    for (int j = 0; j < BINS; ++j) f2[j] = qx1(et[j]);

    float acc[CONV_N];
#pragma unroll
    for (int j = 0; j < CONV_N; ++j) acc[j] = 0.f;
#pragma unroll
    for (int k = 0; k < BINS; ++k)
#pragma unroll
        for (int m = 0; m < BINS; ++m)
            acc[k + m] = fmaf(et[k], f2[m], acc[k + m]);
    // lanes 0,1 of each quad hold tb; lanes 2,3 hold lr (conv commutes)

    __syncthreads();  // all row ds_reads of sA are long done -> overlay safe
    float* sR = sA;   // ratio repack overlays pred tile (1056 of 2176 floats)

    const int r = tid & 3;
    const int g = tid >> 2;
    // xor-2 swap OUTSIDE the guard (DPP needs all lanes active);
    // lanes 0,1: ratio = lr / (tb + eps). Lane 0 stores j<17, lane 1 rest.
#pragma unroll
    for (int j = 0; j < CONV_N; ++j) {
        const float o = qx2(acc[j]);
        if (r == (j < BINS ? 0 : 1))
            sR[g * CONV_N + j] = o * __builtin_amdgcn_rcpf(acc[j] + 1e-8f);
    }
    __syncthreads();

    // ---- coalesced store of the 1056 ratio floats ----
    const long long ob = 1 + (long long)blockIdx.x * (GPB * CONV_N);
#pragma unroll
    for (int i = 0; i < 8; ++i)
        out[ob + i * RPB + tid] = sR[i * RPB + tid];
    if (tid < 32) out[ob + 1024 + tid] = sR[1024 + tid];
}

// PART=true: reduce 2*16384 partials; else just combine the two atomics.
template <bool PART>
__global__ __launch_bounds__(1024) void kd_reduce(
    const float* __restrict__ ws, float* __restrict__ out)
{
    if (!PART) {
        if (threadIdx.x == 0)
            out[0] = 100.0f * (ws[0] * (1.0f / ROWS)) * (ws[1] * (1.0f / ROWS));
        return;
    }
    __shared__ float red[32];
    const int tid = threadIdx.x;
    const float4* k4 = reinterpret_cast<const float4*>(ws);           // 4096 f4
    const float4* w4 = reinterpret_cast<const float4*>(ws + NPART);   // 4096 f4
    float ks = 0.f, wsum = 0.f;
#pragma unroll
    for (int i = 0; i < 4; ++i) {
        const float4 a = k4[i * 1024 + tid];
        const float4 b = w4[i * 1024 + tid];
        ks += (a.x + a.y) + (a.z + a.w);
        wsum += (b.x + b.y) + (b.z + b.w);
    }
#pragma unroll
    for (int off = 32; off >= 1; off >>= 1) {
        ks += __shfl_down(ks, off, 64);
        wsum += __shfl_down(wsum, off, 64);
    }
    if ((tid & 63) == 0) {
        red[(tid >> 6) * 2 + 0] = ks;
        red[(tid >> 6) * 2 + 1] = wsum;
    }
    __syncthreads();
    if (tid == 0) {
        float K = 0.f, W = 0.f;
#pragma unroll
        for (int i = 0; i < 16; ++i) { K += red[2 * i]; W += red[2 * i + 1]; }
        out[0] = 100.0f * (K * (1.0f / ROWS)) * (W * (1.0f / ROWS));
    }
}

extern "C" void kernel_launch(void* const* d_in, const int* in_sizes, int n_in,
                              void* d_out, int out_size, void* d_ws, size_t ws_size,
                              hipStream_t stream)
{
    const float* pred   = (const float*)d_in[0];
    const float* soft   = (const float*)d_in[1];
    const float* weight = (const float*)d_in[2];
    float* out = (float*)d_out;
    float* ws  = (float*)d_ws;

    if (ws_size >= (size_t)(2 * NPART) * sizeof(float)) {
        kd_main<true><<<NBLK, RPB, 0, stream>>>(pred, soft, weight, out, ws);
        kd_reduce<true><<<1, 1024, 0, stream>>>(ws, out);
    } else {
        hipMemsetAsync(ws, 0, 2 * sizeof(float), stream);
        kd_main<false><<<NBLK, RPB, 0, stream>>>(pred, soft, weight, out, ws);
        kd_reduce<false><<<1, 1024, 0, stream>>>(ws, out);
    }
}

// Round 6
// 182.089 us; speedup vs baseline: 1.0048x; 1.0048x over previous
//
#include <hip/hip_runtime.h>

#define ROWS 1048576
#define BINS 17
#define RPB 128                 // rows per block = threads per block (2 waves)
#define NBLK (ROWS / RPB)       // 8192 blocks
#define NPART (2 * NBLK)        // 16384 partials per quantity (one per wave)
#define GPB (RPB / 4)           // 32 conv groups per block
#define CONV_N 33               // 2*BINS - 1
#define L2E 1.442695040888963f
#define LN2 0.6931471805599453f

// Round-6: MLP fix. All five prior structures tied at 67-70us = 177 MB
// (142.6 read + 34.6 write) / 2.6 TB/s — an effective-BW wall, not HBM
// (74 vs 110 MB HBM fetch -> identical time), not occupancy (37->62% -> 0),
// not barriers, not TA coalescing. Mechanism: staging as load->VGPR->
// ds_write forces vmcnt waits between pairs -> ~2-3 loads in flight/wave
// (~2 KB/CU vs the ~9.4 KB Little's-law needs for 6.3 TB/s). Fix: direct
// global->LDS DMA via __builtin_amdgcn_global_load_lds width=16 — fire-and-
// forget, zero VGPR round-trip, single vmcnt drain at the barrier, so all
// ~8.5 KB/wave of staging stays in flight. LDS dest is wave-uniform base +
// lane*16 (HW rule) — our linear float4 layout matches exactly.
// launch_bounds(128,2): 256-VGPR cap removes any conv-acc spill ambiguity.

__device__ __forceinline__ void gl_lds16(const float4* g, float4* l) {
    __builtin_amdgcn_global_load_lds(
        (const __attribute__((address_space(1))) void*)g,
        (__attribute__((address_space(3))) void*)l, 16, 0, 0);
}

__device__ __forceinline__ float qx1(float v) {   // quad_perm lane^1
    return __int_as_float(__builtin_amdgcn_update_dpp(
        0, __float_as_int(v), 0xB1, 0xF, 0xF, true));
}
__device__ __forceinline__ float qx2(float v) {   // quad_perm lane^2
    return __int_as_float(__builtin_amdgcn_update_dpp(
        0, __float_as_int(v), 0x4E, 0xF, 0xF, true));
}

template <bool PART>
__global__ __launch_bounds__(128, 2) void kd_main(
    const float* __restrict__ pred,
    const float* __restrict__ soft,
    const float* __restrict__ weight,
    float* __restrict__ out,
    float* __restrict__ ws)
{
    __shared__ float sA[RPB * BINS];  // pred tile; later ratio repack overlay
    __shared__ float sB[RPB * BINS];  // soft tile
    const int tid  = threadIdx.x;
    const int wv   = tid >> 6;
    const int lane = tid & 63;
    const long long base = (long long)blockIdx.x * (RPB * BINS);

    // ---- async staging: 544 float4 per tile, direct global->LDS ----
    const float4* p4 = reinterpret_cast<const float4*>(pred + base);
    const float4* q4 = reinterpret_cast<const float4*>(soft + base);
    float4* a4 = reinterpret_cast<float4*>(sA);
    float4* b4 = reinterpret_cast<float4*>(sB);
#pragma unroll
    for (int k = 0; k < 4; ++k) {
        const int o = k * RPB + wv * 64;     // wave-uniform LDS base
        gl_lds16(p4 + o + lane, a4 + o);
        gl_lds16(q4 + o + lane, b4 + o);
    }
    if (tid < 32) {                          // tail: wave 0, lanes 0-31
        gl_lds16(p4 + 512 + lane, a4 + 512);
        gl_lds16(q4 + 512 + lane, b4 + 512);
    }
    const float w = weight[blockIdx.x * RPB + tid];
    __syncthreads();   // compiler drains vmcnt(0) before s_barrier

    // ---- per-row register loads from LDS (68 B contiguous per thread) ----
    float x[BINS], y[BINS];
#pragma unroll
    for (int j = 0; j < BINS; ++j) x[j] = sA[tid * BINS + j];
#pragma unroll
    for (int j = 0; j < BINS; ++j) y[j] = sB[tid * BINS + j];

    // ---- one-pass stats ----
    float sx = 0.f, sy = 0.f, sxx = 0.f, syy = 0.f;
    float xmx = -1e30f, ymx = -1e30f;
#pragma unroll
    for (int j = 0; j < BINS; ++j) {
        sx += x[j]; sxx = fmaf(x[j], x[j], sxx); xmx = fmaxf(xmx, x[j]);
        sy += y[j]; syy = fmaf(y[j], y[j], syy); ymx = fmaxf(ymx, y[j]);
    }
    const float mx = sx * (1.0f / BINS);
    const float my = sy * (1.0f / BINS);
    const float vx = fmaxf(fmaf(-sx, mx, sxx), 0.f) * (1.0f / (BINS - 1));
    const float vy = fmaxf(fmaf(-sy, my, syy), 0.f) * (1.0f / (BINS - 1));
    // scale = (1/T) * log2(e) / (eps + std); exp2 arg = (v - vmax) * scale
    const float sxl = (0.1f * L2E) *
        __builtin_amdgcn_rcpf(1e-7f + __builtin_amdgcn_sqrtf(vx));
    const float syl = (0.1f * L2E) *
        __builtin_amdgcn_rcpf(1e-7f + __builtin_amdgcn_sqrtf(vy));
    const float cA = -xmx * sxl;
    const float cB = -ymx * syl;
    const float cT = -ymx * L2E;      // raw-y softmax, exp2 units

    // ---- fused exp pass; target exps stay in registers ----
    float et[BINS];
    float sea = 0.f, seb = 0.f, ts = 0.f, sdb = 0.f;
#pragma unroll
    for (int j = 0; j < BINS; ++j) {
        const float aj = fmaf(x[j], sxl, cA);          // log2 student logits
        const float bj = fmaf(y[j], syl, cB);          // log2 teacher logits
        const float ea = exp2f(aj);
        const float eb = exp2f(bj);
        const float tv = exp2f(fmaf(y[j], L2E, cT));
        sea += ea; seb += eb; ts += tv;
        sdb = fmaf(eb, bj - aj, sdb);                  // sum eb*(bj-aj), log2
        et[j] = tv;
    }
    // KL = ln2 * ( sum(eb*(bj-aj))/seb + log2(sea) - log2(seb) )
    const float kl = LN2 * (sdb * __builtin_amdgcn_rcpf(seb)
                            + (__log2f(sea) - __log2f(seb)));
    const float invts = __builtin_amdgcn_rcpf(ts);
#pragma unroll
    for (int j = 0; j < BINS; ++j) et[j] *= invts;     // normalized softmax

    // ---- per-wave reduce kl & weight; one partial pair per wave ----
    float k2 = kl, w2 = w;
#pragma unroll
    for (int off = 32; off >= 1; off >>= 1) {
        k2 += __shfl_down(k2, off, 64);
        w2 += __shfl_down(w2, off, 64);
    }
    if ((tid & 63) == 0) {
        if (PART) {
            ws[2 * blockIdx.x + wv]         = k2;
            ws[NPART + 2 * blockIdx.x + wv] = w2;
        } else {
            atomicAdd(&ws[0], k2);
            atomicAdd(&ws[1], w2);
        }
    }

    // ---- in-quad conv, no LDS, no barrier: partner row via quad_perm ----
    float f2[BINS];
#pragma unroll
    for (int j = 0; j < BINS; ++j) f2[j] = qx1(et[j]);

    float acc[CONV_N];
#pragma unroll
    for (int j = 0; j < CONV_N; ++j) acc[j] = 0.f;
#pragma unroll
    for (int k = 0; k < BINS; ++k)
#pragma unroll
        for (int m = 0; m < BINS; ++m)
            acc[k + m] = fmaf(et[k], f2[m], acc[k + m]);
    // lanes 0,1 of each quad hold tb; lanes 2,3 hold lr (conv commutes)

    __syncthreads();  // all row ds_reads of sA done -> overlay safe
    float* sR = sA;   // ratio repack overlays pred tile (1056 of 2176 floats)

    const int r = tid & 3;
    const int g = tid >> 2;
    // xor-2 swap OUTSIDE the guard (DPP needs all lanes active);
    // lanes 0,1: ratio = lr / (tb + eps). Lane 0 stores j<17, lane 1 rest.
#pragma unroll
    for (int j = 0; j < CONV_N; ++j) {
        const float o = qx2(acc[j]);
        if (r == (j < BINS ? 0 : 1))
            sR[g * CONV_N + j] = o * __builtin_amdgcn_rcpf(acc[j] + 1e-8f);
    }
    __syncthreads();

    // ---- coalesced store of the 1056 ratio floats ----
    const long long ob = 1 + (long long)blockIdx.x * (GPB * CONV_N);
#pragma unroll
    for (int i = 0; i < 8; ++i)
        out[ob + i * RPB + tid] = sR[i * RPB + tid];
    if (tid < 32) out[ob + 1024 + tid] = sR[1024 + tid];
}

// PART=true: reduce 2*16384 partials; else just combine the two atomics.
template <bool PART>
__global__ __launch_bounds__(1024) void kd_reduce(
    const float* __restrict__ ws, float* __restrict__ out)
{
    if (!PART) {
        if (threadIdx.x == 0)
            out[0] = 100.0f * (ws[0] * (1.0f / ROWS)) * (ws[1] * (1.0f / ROWS));
        return;
    }
    __shared__ float red[32];
    const int tid = threadIdx.x;
    const float4* k4 = reinterpret_cast<const float4*>(ws);           // 4096 f4
    const float4* w4 = reinterpret_cast<const float4*>(ws + NPART);   // 4096 f4
    float ks = 0.f, wsum = 0.f;
#pragma unroll
    for (int i = 0; i < 4; ++i) {
        const float4 a = k4[i * 1024 + tid];
        const float4 b = w4[i * 1024 + tid];
        ks += (a.x + a.y) + (a.z + a.w);
        wsum += (b.x + b.y) + (b.z + b.w);
    }
#pragma unroll
    for (int off = 32; off >= 1; off >>= 1) {
        ks += __shfl_down(ks, off, 64);
        wsum += __shfl_down(wsum, off, 64);
    }
    if ((tid & 63) == 0) {
        red[(tid >> 6) * 2 + 0] = ks;
        red[(tid >> 6) * 2 + 1] = wsum;
    }
    __syncthreads();
    if (tid == 0) {
        float K = 0.f, W = 0.f;
#pragma unroll
        for (int i = 0; i < 16; ++i) { K += red[2 * i]; W += red[2 * i + 1]; }
        out[0] = 100.0f * (K * (1.0f / ROWS)) * (W * (1.0f / ROWS));
    }
}

extern "C" void kernel_launch(void* const* d_in, const int* in_sizes, int n_in,
                              void* d_out, int out_size, void* d_ws, size_t ws_size,
                              hipStream_t stream)
{
    const float* pred   = (const float*)d_in[0];
    const float* soft   = (const float*)d_in[1];
    const float* weight = (const float*)d_in[2];
    float* out = (float*)d_out;
    float* ws  = (float*)d_ws;

    if (ws_size >= (size_t)(2 * NPART) * sizeof(float)) {
        kd_main<true><<<NBLK, RPB, 0, stream>>>(pred, soft, weight, out, ws);
        kd_reduce<true><<<1, 1024, 0, stream>>>(ws, out);
    } else {
        hipMemsetAsync(ws, 0, 2 * sizeof(float), stream);
        kd_main<false><<<NBLK, RPB, 0, stream>>>(pred, soft, weight, out, ws);
        kd_reduce<false><<<1, 1024, 0, stream>>>(ws, out);
    }
}